// Round 2
// baseline (695.638 us; speedup 1.0000x reference)
//
#include <hip/hip_runtime.h>

// Problem constants
#define EDIM 256
#define NE   1024
#define NROWS 65536        // 16 * 64 * 64
#define HW   4096          // 64*64

// d_out layout (fp32 elements): z_q[16777216], loss, perplexity, idx[65536]
#define ZQ_OFF   0
#define LOSS_OFF 16777216
#define PERP_OFF 16777217
#define IDX_OFF  16777218

// ws layout (byte offsets)
#define WS_ET     0                          // eT [256][1024] f32, 1 MiB
#define WS_BNORM  (1024*1024)                // 1024 f32 (numpy-pairwise ||e||^2)
#define WS_COUNTS (WS_BNORM + 4096)          // 1024 i32
#define WS_LOSS   (WS_COUNTS + 4096)         // double
#define WS_IDX    (WS_LOSS + 16)             // 65536 i32
#define WS_AN     (WS_IDX + 65536*4)         // 65536 f32 (numpy-pairwise ||z||^2)

// ---------------------------------------------------------------------------
// numpy pairwise_sum replica for a 128-element block of squares:
// 8 accumulators, 16 sequential steps each, combine ((r0+r1)+(r2+r3))+((r4+r5)+(r6+r7)).
// contract(off): square must round BEFORE the add (numpy materializes zf*zf).
// ---------------------------------------------------------------------------
__device__ __forceinline__ float np_half128(const float* __restrict__ p, long stride) {
#pragma clang fp contract(off)
    float r[8];
#pragma unroll
    for (int j = 0; j < 8; ++j) { float v = p[(long)j * stride]; r[j] = v * v; }
    for (int i = 8; i < 128; i += 8) {
#pragma unroll
        for (int j = 0; j < 8; ++j) { float v = p[(long)(i + j) * stride]; r[j] += v * v; }
    }
    return ((r[0] + r[1]) + (r[2] + r[3])) + ((r[4] + r[5]) + (r[6] + r[7]));
}

// ---------------------------------------------------------------------------
// K0: transpose embedding e[1024][256] -> eT[256][1024]
// ---------------------------------------------------------------------------
__global__ void k_transpose(const float* __restrict__ e, float* __restrict__ eT) {
    int t = blockIdx.x * 256 + threadIdx.x;   // 262144 threads
    int c = t >> 10;
    int j = t & 1023;
    eT[t] = e[j * EDIM + c];
}

// ---------------------------------------------------------------------------
// K1: B_j = numpy-pairwise sum of e[j][:]^2  (n=256 -> half(0..127)+half(128..255))
// ---------------------------------------------------------------------------
__global__ void k_bnorm(const float* __restrict__ e, float* __restrict__ Bn) {
    int j = blockIdx.x * 256 + threadIdx.x;   // grid 4
    const float* p = e + (size_t)j * EDIM;
    float h0 = np_half128(p, 1);
    float h1 = np_half128(p + 128, 1);
    Bn[j] = h0 + h1;
}

// ---------------------------------------------------------------------------
// K2: A_n = numpy-pairwise sum of zf[n][:]^2 (strided by HW in z's layout)
// ---------------------------------------------------------------------------
__global__ void k_rownorm(const float* __restrict__ z, float* __restrict__ An) {
    int n = blockIdx.x * 256 + threadIdx.x;   // grid 256
    int b = n >> 12, hw = n & 4095;
    const float* p = z + (size_t)b * (EDIM * HW) + hw;
    float h0 = np_half128(p, HW);
    float h1 = np_half128(p + (size_t)128 * HW, HW);
    An[n] = h0 + h1;
}

// ---------------------------------------------------------------------------
// K3: distance GEMM + argmin replicating np-fp32 semantics:
//   d_hat = fl( fl(A_n + B_j) - fl(2*D_nj) ), argmin with first-index tie-break.
// Block: 256 threads; tile 128 rows x all 1024 codes; 8x8 register tiles.
// ---------------------------------------------------------------------------
__global__ void k_dist(const float* __restrict__ z, const float* __restrict__ eT,
                       const float* __restrict__ Bn, const float* __restrict__ An,
                       int* __restrict__ idxw, float* __restrict__ out) {
    __shared__ float4 As[32 * 32];   // [k][m4]: 32 k x 128 rows
    __shared__ float4 Bs[32 * 32];   // [k][j4]: 32 k x 128 codes

    const int t  = threadIdx.x;
    const int tx = t & 15, ty = t >> 4;
    const int n0 = blockIdx.x * 128;          // 512 blocks
    const int b  = n0 >> 12;
    const int hw0 = n0 & 4095;
    const float* zb = z + (size_t)b * (EDIM * HW) + hw0;

    float an[8];
#pragma unroll
    for (int r = 0; r < 8; ++r) {
        int row = (r >> 2) * 64 + ty * 4 + (r & 3);
        an[r] = An[n0 + row];
    }

    float m1[8];
    int   i1[8];
#pragma unroll
    for (int r = 0; r < 8; ++r) { m1[r] = 1e30f; i1[r] = 0; }

    for (int jt = 0; jt < 8; ++jt) {
        float acc[8][8];
#pragma unroll
        for (int r = 0; r < 8; ++r)
#pragma unroll
            for (int c = 0; c < 8; ++c) acc[r][c] = 0.f;

        for (int kc = 0; kc < 8; ++kc) {
            __syncthreads();
#pragma unroll
            for (int i = 0; i < 4; ++i) {
                int l4 = t + i * 256;
                int k  = l4 >> 5, m4 = l4 & 31;
                As[l4] = *(const float4*)(zb + (kc * 32 + k) * HW + m4 * 4);
                Bs[l4] = *(const float4*)(eT + (kc * 32 + k) * NE + jt * 128 + m4 * 4);
            }
            __syncthreads();
#pragma unroll 4
            for (int k = 0; k < 32; ++k) {
                float4 a0 = As[k * 32 + ty];
                float4 a1 = As[k * 32 + 16 + ty];
                float4 b0 = Bs[k * 32 + tx];
                float4 b1 = Bs[k * 32 + 16 + tx];
                float av[8] = {a0.x, a0.y, a0.z, a0.w, a1.x, a1.y, a1.z, a1.w};
                float bv[8] = {b0.x, b0.y, b0.z, b0.w, b1.x, b1.y, b1.z, b1.w};
#pragma unroll
                for (int r = 0; r < 8; ++r)
#pragma unroll
                    for (int c = 0; c < 8; ++c)
                        acc[r][c] = __builtin_fmaf(av[r], bv[c], acc[r][c]);
            }
        }

        // fold distances for this code tile, np-fp32-faithful
        float4 en0 = *(const float4*)(Bn + jt * 128 + tx * 4);
        float4 en1 = *(const float4*)(Bn + jt * 128 + 64 + tx * 4);
        float en[8] = {en0.x, en0.y, en0.z, en0.w, en1.x, en1.y, en1.z, en1.w};
        {
#pragma clang fp contract(off)
#pragma unroll
            for (int r = 0; r < 8; ++r) {
#pragma unroll
                for (int c = 0; c < 8; ++c) {
                    float t2 = acc[r][c] + acc[r][c];   // fl(2*D), exact doubling
                    float s  = an[r] + en[c];           // fl(A+B)
                    float d  = s - t2;                  // fl(s - t)
                    int jcode = jt * 128 + (c >> 2) * 64 + tx * 4 + (c & 3);
                    // within-thread scan is ascending jcode; strict < keeps first min
                    if (d < m1[r]) { m1[r] = d; i1[r] = jcode; }
                }
            }
        }
    }

    // cross-lane lexicographic (value, index) min over the 16 tx lanes per row
#pragma unroll
    for (int r = 0; r < 8; ++r) {
        float v = m1[r];
        int  ii = i1[r];
#pragma unroll
        for (int s = 1; s < 16; s <<= 1) {
            float ov = __shfl_xor(v, s, 64);
            int   oi = __shfl_xor(ii, s, 64);
            if (ov < v || (ov == v && oi < ii)) { v = ov; ii = oi; }
        }
        if (tx == 0) {
            int row = (r >> 2) * 64 + ty * 4 + (r & 3);
            int n = n0 + row;
            idxw[n] = ii;
            out[IDX_OFF + n] = (float)ii;
        }
    }
}

// ---------------------------------------------------------------------------
// K4: histogram of idx
// ---------------------------------------------------------------------------
__global__ void k_hist(const int* __restrict__ idxw, int* __restrict__ counts) {
    int t = blockIdx.x * 256 + threadIdx.x;   // grid 256
    atomicAdd(&counts[idxw[t]], 1);
}

// ---------------------------------------------------------------------------
// K5: gather z_q (write [B,C,H,W]) + loss = sum (zq - z)^2
// ---------------------------------------------------------------------------
__global__ void k_gather(const float* __restrict__ z, const float* __restrict__ e,
                         const int* __restrict__ idxw, float* __restrict__ out,
                         double* __restrict__ loss_sum) {
    __shared__ float Ls[256][17];
    __shared__ int   jrow[256];
    __shared__ float red[4];
    int t = threadIdx.x;
    int n0 = blockIdx.x * 256;                // grid 256
    int b = n0 >> 12, hw0 = n0 & 4095;
    jrow[t] = idxw[n0 + t];
    const float* zb = z + (size_t)b * (EDIM * HW) + hw0;
    float* zq = out + (size_t)b * (EDIM * HW) + hw0;
    float lacc = 0.f;

    for (int cc = 0; cc < EDIM; cc += 16) {
        __syncthreads();
#pragma unroll
        for (int i = 0; i < 4; ++i) {
            int l4 = t + i * 256;
            int r = l4 >> 2, c4 = l4 & 3;
            float4 v = *(const float4*)(e + jrow[r] * EDIM + cc + c4 * 4);
            Ls[r][c4 * 4 + 0] = v.x;
            Ls[r][c4 * 4 + 1] = v.y;
            Ls[r][c4 * 4 + 2] = v.z;
            Ls[r][c4 * 4 + 3] = v.w;
        }
        __syncthreads();
#pragma unroll
        for (int i = 0; i < 16; ++i) {
            int c = cc + i;
            float zv = zb[c * HW + t];
            float ev = Ls[t][i];
            float dv = ev - zv;
            lacc = __builtin_fmaf(dv, dv, lacc);
            zq[c * HW + t] = ev;
        }
    }
#pragma unroll
    for (int s = 1; s < 64; s <<= 1) lacc += __shfl_xor(lacc, s, 64);
    if ((t & 63) == 0) red[t >> 6] = lacc;
    __syncthreads();
    if (t == 0)
        atomicAdd(loss_sum, (double)(red[0] + red[1] + red[2] + red[3]));
}

// ---------------------------------------------------------------------------
// K6: finalize loss + perplexity scalars
// ---------------------------------------------------------------------------
__global__ void k_final(const int* __restrict__ counts, const double* __restrict__ loss_sum,
                        float* __restrict__ out) {
    __shared__ float sred[4];
    int t = threadIdx.x;
    float s = 0.f;
    for (int q = 0; q < 4; ++q) {
        float p = (float)counts[q * 256 + t] * (1.0f / 65536.0f);
        s += p * logf(p + 1e-10f);
    }
#pragma unroll
    for (int sh = 1; sh < 64; sh <<= 1) s += __shfl_xor(s, sh, 64);
    if ((t & 63) == 0) sred[t >> 6] = s;
    __syncthreads();
    if (t == 0) {
        out[PERP_OFF] = expf(-(sred[0] + sred[1] + sred[2] + sred[3]));
        out[LOSS_OFF] = (float)(*loss_sum * 1.25 / 16777216.0);
    }
}

extern "C" void kernel_launch(void* const* d_in, const int* in_sizes, int n_in,
                              void* d_out, int out_size, void* d_ws, size_t ws_size,
                              hipStream_t stream) {
    const float* z = (const float*)d_in[0];
    const float* e = (const float*)d_in[1];
    float* out = (float*)d_out;
    char* ws = (char*)d_ws;

    float*  eT       = (float*)(ws + WS_ET);
    float*  Bn       = (float*)(ws + WS_BNORM);
    int*    counts   = (int*)(ws + WS_COUNTS);
    double* loss_sum = (double*)(ws + WS_LOSS);
    int*    idxw     = (int*)(ws + WS_IDX);
    float*  An       = (float*)(ws + WS_AN);

    // zero counts + loss accumulator (contiguous region)
    hipMemsetAsync(ws + WS_COUNTS, 0, 4096 + 16, stream);

    k_transpose<<<1024, 256, 0, stream>>>(e, eT);
    k_bnorm<<<4, 256, 0, stream>>>(e, Bn);
    k_rownorm<<<256, 256, 0, stream>>>(z, An);
    k_dist<<<512, 256, 0, stream>>>(z, eT, Bn, An, idxw, out);
    k_hist<<<256, 256, 0, stream>>>(idxw, counts);
    k_gather<<<256, 256, 0, stream>>>(z, e, idxw, out, loss_sum);
    k_final<<<1, 256, 0, stream>>>(counts, loss_sum, out);
}

// Round 3
// 517.587 us; speedup vs baseline: 1.3440x; 1.3440x over previous
//
#include <hip/hip_runtime.h>

typedef _Float16 half8 __attribute__((ext_vector_type(8)));
typedef float f32x4 __attribute__((ext_vector_type(4)));

// Problem constants
#define EDIM 256
#define NE   1024
#define HW   4096

// d_out layout (fp32 elements): z_q[16777216], loss, perplexity, idx[65536]
#define ZQ_OFF   0
#define LOSS_OFF 16777216
#define PERP_OFF 16777217
#define IDX_OFF  16777218

// ws layout (byte offsets)
#define WS_ESPH    0                         // esp_hi [8 kc][1024 j][32 k] f16, 512 KB
#define WS_ESPL    (512*1024)                // esp_lo, 512 KB
#define WS_BNORM   (1024*1024)               // 1024 f32
#define WS_COUNTS  (WS_BNORM + 4096)         // 1024 i32
#define WS_COUNTER (WS_COUNTS + 4096)        // i32 (+pad)
#define WS_LOSS    (WS_COUNTER + 16)         // double
#define WS_AN      (WS_LOSS + 16)            // 65536 f32
#define WS_IDX     (WS_AN + 65536*4)         // 65536 i32
#define WS_LIST    (WS_IDX + 65536*4)        // 65536 i32

// refine margin: must exceed 2*(|d_approx - d_numpy|_max) ~ 2*(bin 3.05e-5 + mfma err ~1e-5)
#define EPS 2.0e-4f
// acc holds 1024*D (e pre-scaled by 1024); 2*D = acc/512
#define SCACC (1.0f/512.0f)

// ---------------------------------------------------------------------------
// numpy pairwise_sum replica for a 128-element block of squares.
// ---------------------------------------------------------------------------
__device__ __forceinline__ float np_half128(const float* __restrict__ p, long stride) {
#pragma clang fp contract(off)
    float r[8];
#pragma unroll
    for (int j = 0; j < 8; ++j) { float v = p[(long)j * stride]; r[j] = v * v; }
    for (int i = 8; i < 128; i += 8) {
#pragma unroll
        for (int j = 0; j < 8; ++j) { float v = p[(long)(i + j) * stride]; r[j] += v * v; }
    }
    return ((r[0] + r[1]) + (r[2] + r[3])) + ((r[4] + r[5]) + (r[6] + r[7]));
}

// ---------------------------------------------------------------------------
// K0: split e*1024 into f16 hi/lo, layout [kc][j][kk] for coalesced LDS staging
// ---------------------------------------------------------------------------
__global__ void k_prep_e(const float* __restrict__ e, _Float16* __restrict__ eh,
                         _Float16* __restrict__ el) {
    int t = blockIdx.x * 256 + threadIdx.x;   // 262144
    int j = t >> 8, c = t & 255;
    float v = e[t] * 1024.0f;                 // exact pow2 scale; e[t] == e[j*256+c]
    _Float16 h = (_Float16)v;
    _Float16 l = (_Float16)(v - (float)h);
    int o = ((c >> 5) * NE + j) * 32 + (c & 31);
    eh[o] = h; el[o] = l;
}

// ---------------------------------------------------------------------------
// K1: B_j = numpy-pairwise sum of e[j][:]^2
// ---------------------------------------------------------------------------
__global__ void k_bnorm(const float* __restrict__ e, float* __restrict__ Bn) {
    int j = blockIdx.x * 256 + threadIdx.x;   // grid 4
    const float* p = e + (size_t)j * EDIM;
    Bn[j] = np_half128(p, 1) + np_half128(p + 128, 1);
}

// ---------------------------------------------------------------------------
// K2: A_n = numpy-pairwise sum of zf[n][:]^2
// ---------------------------------------------------------------------------
__global__ void k_rownorm(const float* __restrict__ z, float* __restrict__ An) {
    int n = blockIdx.x * 256 + threadIdx.x;   // grid 256
    int b = n >> 12, hw = n & 4095;
    const float* p = z + (size_t)b * (EDIM * HW) + hw;
    An[n] = np_half128(p, HW) + np_half128(p + (size_t)128 * HW, HW);
}

// ---------------------------------------------------------------------------
// K3: MFMA distance GEMM (split-f16, 3 terms) + top-2 argmin + refine flags.
// Block: 256 thr / 4 waves; 128 rows x 1024 codes. Wave w owns rows w*32..+31.
// A fragments (z rows) in registers; B (codes) staged in LDS per (jt,kc),
// padded stride 40 f16 -> 2-way bank aliasing (free).
// ---------------------------------------------------------------------------
__global__ __launch_bounds__(256, 2) void k_dist(
    const float* __restrict__ z, const _Float16* __restrict__ eh,
    const _Float16* __restrict__ el, const float* __restrict__ Bn,
    const float* __restrict__ An, int* __restrict__ idxw,
    float* __restrict__ out, int* __restrict__ counter, int* __restrict__ list)
{
    __shared__ half8 BsH[128 * 5];   // 10240 B
    __shared__ half8 BsL[128 * 5];

    const int t  = threadIdx.x;
    const int w  = t >> 6;
    const int L  = t & 63;
    const int lm = L & 15;
    const int q  = L >> 4;
    const int n0 = blockIdx.x * 128;          // 512 blocks
    const int b  = n0 >> 12, hw0 = n0 & 4095;
    const float* zb = z + (size_t)b * (EDIM * HW) + hw0;
    const int rbase = w * 32;

    // A fragments: [mt][kc], layout A[m=lane&15][k=quad*8+j]
    half8 Ah[2][8], Al[2][8];
#pragma unroll
    for (int mt = 0; mt < 2; ++mt) {
        int row = rbase + mt * 16 + lm;
#pragma unroll
        for (int kc = 0; kc < 8; ++kc) {
            float av[8];
#pragma unroll
            for (int j = 0; j < 8; ++j)
                av[j] = zb[(kc * 32 + q * 8 + j) * HW + row];
#pragma unroll
            for (int j = 0; j < 8; ++j) {
                _Float16 h = (_Float16)av[j];
                Ah[mt][kc][j] = h;
                Al[mt][kc][j] = (_Float16)(av[j] - (float)h);
            }
        }
    }

    // row norms for the 8 rows this lane's C-fragments cover
    float an[8];
#pragma unroll
    for (int mt = 0; mt < 2; ++mt)
#pragma unroll
        for (int r = 0; r < 4; ++r)
            an[mt * 4 + r] = An[n0 + rbase + mt * 16 + q * 4 + r];

    float m1[8], m2[8]; int i1[8];
#pragma unroll
    for (int r = 0; r < 8; ++r) { m1[r] = 1e30f; m2[r] = 1e30f; i1[r] = 0; }

    const half8* ghv = (const half8*)eh;
    const half8* glv = (const half8*)el;

    for (int jt = 0; jt < 8; ++jt) {
        f32x4 acc[2][8];
#pragma unroll
        for (int mt = 0; mt < 2; ++mt)
#pragma unroll
            for (int nt = 0; nt < 8; ++nt)
                acc[mt][nt] = (f32x4){0.f, 0.f, 0.f, 0.f};

        float en[8];
#pragma unroll
        for (int nt = 0; nt < 8; ++nt) en[nt] = Bn[jt * 128 + nt * 16 + lm];

        for (int kc = 0; kc < 8; ++kc) {
            __syncthreads();
            {   // stage 128 codes x 32 k (hi+lo): thread -> 2 half8 each array
                int cr = t >> 1, hf = t & 1;
                int gi = (kc * NE + jt * 128 + cr) * 4 + hf * 2;
                int li = cr * 5 + hf * 2;
                BsH[li]     = ghv[gi];
                BsH[li + 1] = ghv[gi + 1];
                BsL[li]     = glv[gi];
                BsL[li + 1] = glv[gi + 1];
            }
            __syncthreads();
#pragma unroll
            for (int nt = 0; nt < 8; ++nt) {
                half8 bh = BsH[(nt * 16 + lm) * 5 + q];
                half8 bl = BsL[(nt * 16 + lm) * 5 + q];
                acc[0][nt] = __builtin_amdgcn_mfma_f32_16x16x32_f16(Ah[0][kc], bh, acc[0][nt], 0, 0, 0);
                acc[0][nt] = __builtin_amdgcn_mfma_f32_16x16x32_f16(Ah[0][kc], bl, acc[0][nt], 0, 0, 0);
                acc[0][nt] = __builtin_amdgcn_mfma_f32_16x16x32_f16(Al[0][kc], bh, acc[0][nt], 0, 0, 0);
                acc[1][nt] = __builtin_amdgcn_mfma_f32_16x16x32_f16(Ah[1][kc], bh, acc[1][nt], 0, 0, 0);
                acc[1][nt] = __builtin_amdgcn_mfma_f32_16x16x32_f16(Ah[1][kc], bl, acc[1][nt], 0, 0, 0);
                acc[1][nt] = __builtin_amdgcn_mfma_f32_16x16x32_f16(Al[1][kc], bh, acc[1][nt], 0, 0, 0);
            }
        }

        // fold: d_approx = (A_n + B_j) - acc/512 ; track top-2 per row
#pragma unroll
        for (int mt = 0; mt < 2; ++mt)
#pragma unroll
            for (int nt = 0; nt < 8; ++nt) {
                int jc = jt * 128 + nt * 16 + lm;
#pragma unroll
                for (int r = 0; r < 4; ++r) {
                    float d = (an[mt * 4 + r] + en[nt]) - acc[mt][nt][r] * SCACC;
                    int r8 = mt * 4 + r;
                    if (d < m1[r8]) { m2[r8] = m1[r8]; m1[r8] = d; i1[r8] = jc; }
                    else if (d < m2[r8]) m2[r8] = d;
                }
            }
    }

    // cross-lane (16 lanes per quad share rows) lexicographic top-2 merge
#pragma unroll
    for (int r8 = 0; r8 < 8; ++r8) {
        float v1 = m1[r8], v2 = m2[r8]; int ii = i1[r8];
#pragma unroll
        for (int s = 1; s < 16; s <<= 1) {
            float o1 = __shfl_xor(v1, s, 64);
            int   oi = __shfl_xor(ii, s, 64);
            float o2 = __shfl_xor(v2, s, 64);
            float hi = fmaxf(v1, o1);
            if (o1 < v1 || (o1 == v1 && oi < ii)) { v1 = o1; ii = oi; }
            v2 = fminf(fminf(v2, o2), hi);
        }
        if (lm == 0) {
            int mt = r8 >> 2, r = r8 & 3;
            int n = n0 + rbase + mt * 16 + q * 4 + r;
            idxw[n] = ii;
            out[IDX_OFF + n] = (float)ii;
            if (v2 - v1 < EPS) {
                int p = atomicAdd(counter, 1);
                if (p < 65536) list[p] = n;
            }
        }
    }
}

// ---------------------------------------------------------------------------
// K4: numpy-bit-faithful fp32 full rescan of flagged rows (16 rows/block-iter).
// Each thread owns codes j == t (mod 256) and accumulates 16 rows at once so
// e is read once per block. Sequential-k fmaf chain == numpy sgemm order.
// ---------------------------------------------------------------------------
__global__ void k_refine(const float* __restrict__ z, const float* __restrict__ e,
                         const float* __restrict__ Bn, const float* __restrict__ An,
                         const int* __restrict__ counter, const int* __restrict__ list,
                         int* __restrict__ idxw, float* __restrict__ out)
{
    __shared__ float zs[16][256];
    __shared__ int   ns[16];
    __shared__ float ans[16];
    __shared__ float pv[4][16];
    __shared__ int   pi[4][16];
    int t = threadIdx.x;
    int cnt = min(*counter, 65536);
    for (int li0 = blockIdx.x * 16; li0 < cnt; li0 += gridDim.x * 16) {
        int nrows = min(16, cnt - li0);
        __syncthreads();
        if (t < 16) {
            int n = (t < nrows) ? list[li0 + t] : list[li0];
            ns[t] = n; ans[t] = An[n];
        }
        __syncthreads();
        for (int u = 0; u < 16; ++u) {
            int n = ns[u];
            zs[u][t] = z[(size_t)(n >> 12) * (EDIM * HW) + (n & 4095) + t * HW];
        }
        __syncthreads();

        float bm[16]; int bi[16];
#pragma unroll
        for (int r = 0; r < 16; ++r) { bm[r] = 1e30f; bi[r] = 1 << 30; }
        for (int p = 0; p < 4; ++p) {
            int j = t + p * 256;
            const float* er = e + (size_t)j * EDIM;
            float D[16];
#pragma unroll
            for (int r = 0; r < 16; ++r) D[r] = 0.f;
            for (int c = 0; c < 256; ++c) {
                float ev = er[c];
#pragma unroll
                for (int r = 0; r < 16; ++r)
                    D[r] = __builtin_fmaf(ev, zs[r][c], D[r]);
            }
            float bnj = Bn[j];
            {
#pragma clang fp contract(off)
#pragma unroll
                for (int r = 0; r < 16; ++r) {
                    float t2 = D[r] + D[r];
                    float s  = ans[r] + bnj;
                    float d  = s - t2;
                    if (d < bm[r]) { bm[r] = d; bi[r] = j; }  // j ascending per thread
                }
            }
        }
        int wv = t >> 6, L = t & 63;
        for (int r = 0; r < 16; ++r) {
            float v = bm[r]; int ii = bi[r];
#pragma unroll
            for (int s = 1; s < 64; s <<= 1) {
                float ov = __shfl_xor(v, s, 64);
                int   oi = __shfl_xor(ii, s, 64);
                if (ov < v || (ov == v && oi < ii)) { v = ov; ii = oi; }
            }
            if (L == 0) { pv[wv][r] = v; pi[wv][r] = ii; }
        }
        __syncthreads();
        if (t < nrows) {
            float v = pv[0][t]; int ii = pi[0][t];
#pragma unroll
            for (int w2 = 1; w2 < 4; ++w2)
                if (pv[w2][t] < v || (pv[w2][t] == v && pi[w2][t] < ii)) { v = pv[w2][t]; ii = pi[w2][t]; }
            int n = ns[t];
            idxw[n] = ii;
            out[IDX_OFF + n] = (float)ii;
        }
    }
}

// ---------------------------------------------------------------------------
// K5: histogram of final idx
// ---------------------------------------------------------------------------
__global__ void k_hist(const int* __restrict__ idxw, int* __restrict__ counts) {
    int t = blockIdx.x * 256 + threadIdx.x;   // grid 256
    atomicAdd(&counts[idxw[t]], 1);
}

// ---------------------------------------------------------------------------
// K6: gather z_q + loss = sum (zq - z)^2
// ---------------------------------------------------------------------------
__global__ void k_gather(const float* __restrict__ z, const float* __restrict__ e,
                         const int* __restrict__ idxw, float* __restrict__ out,
                         double* __restrict__ loss_sum) {
    __shared__ float Ls[256][17];
    __shared__ int   jrow[256];
    __shared__ float red[4];
    int t = threadIdx.x;
    int n0 = blockIdx.x * 256;                // grid 256
    int b = n0 >> 12, hw0 = n0 & 4095;
    jrow[t] = idxw[n0 + t];
    const float* zb = z + (size_t)b * (EDIM * HW) + hw0;
    float* zq = out + (size_t)b * (EDIM * HW) + hw0;
    float lacc = 0.f;

    for (int cc = 0; cc < EDIM; cc += 16) {
        __syncthreads();
#pragma unroll
        for (int i = 0; i < 4; ++i) {
            int l4 = t + i * 256;
            int r = l4 >> 2, c4 = l4 & 3;
            float4 v = *(const float4*)(e + jrow[r] * EDIM + cc + c4 * 4);
            Ls[r][c4 * 4 + 0] = v.x;
            Ls[r][c4 * 4 + 1] = v.y;
            Ls[r][c4 * 4 + 2] = v.z;
            Ls[r][c4 * 4 + 3] = v.w;
        }
        __syncthreads();
#pragma unroll
        for (int i = 0; i < 16; ++i) {
            int c = cc + i;
            float zv = zb[c * HW + t];
            float ev = Ls[t][i];
            float dv = ev - zv;
            lacc = __builtin_fmaf(dv, dv, lacc);
            zq[c * HW + t] = ev;
        }
    }
#pragma unroll
    for (int s = 1; s < 64; s <<= 1) lacc += __shfl_xor(lacc, s, 64);
    if ((t & 63) == 0) red[t >> 6] = lacc;
    __syncthreads();
    if (t == 0)
        atomicAdd(loss_sum, (double)(red[0] + red[1] + red[2] + red[3]));
}

// ---------------------------------------------------------------------------
// K7: finalize scalars
// ---------------------------------------------------------------------------
__global__ void k_final(const int* __restrict__ counts, const double* __restrict__ loss_sum,
                        float* __restrict__ out) {
    __shared__ float sred[4];
    int t = threadIdx.x;
    float s = 0.f;
    for (int qq = 0; qq < 4; ++qq) {
        float p = (float)counts[qq * 256 + t] * (1.0f / 65536.0f);
        s += p * logf(p + 1e-10f);
    }
#pragma unroll
    for (int sh = 1; sh < 64; sh <<= 1) s += __shfl_xor(s, sh, 64);
    if ((t & 63) == 0) sred[t >> 6] = s;
    __syncthreads();
    if (t == 0) {
        out[PERP_OFF] = expf(-(sred[0] + sred[1] + sred[2] + sred[3]));
        out[LOSS_OFF] = (float)(*loss_sum * 1.25 / 16777216.0);
    }
}

extern "C" void kernel_launch(void* const* d_in, const int* in_sizes, int n_in,
                              void* d_out, int out_size, void* d_ws, size_t ws_size,
                              hipStream_t stream) {
    const float* z = (const float*)d_in[0];
    const float* e = (const float*)d_in[1];
    float* out = (float*)d_out;
    char* ws = (char*)d_ws;

    _Float16* eh      = (_Float16*)(ws + WS_ESPH);
    _Float16* el      = (_Float16*)(ws + WS_ESPL);
    float*    Bn      = (float*)(ws + WS_BNORM);
    int*      counts  = (int*)(ws + WS_COUNTS);
    int*      counter = (int*)(ws + WS_COUNTER);
    double*   loss_sum= (double*)(ws + WS_LOSS);
    float*    An      = (float*)(ws + WS_AN);
    int*      idxw    = (int*)(ws + WS_IDX);
    int*      list    = (int*)(ws + WS_LIST);

    // zero counts + counter + loss accumulator (contiguous)
    hipMemsetAsync(ws + WS_COUNTS, 0, 4096 + 16 + 16, stream);

    k_prep_e <<<1024, 256, 0, stream>>>(e, eh, el);
    k_bnorm  <<<4,    256, 0, stream>>>(e, Bn);
    k_rownorm<<<256,  256, 0, stream>>>(z, An);
    k_dist   <<<512,  256, 0, stream>>>(z, eh, el, Bn, An, idxw, out, counter, list);
    k_refine <<<256,  256, 0, stream>>>(z, e, Bn, An, counter, list, idxw, out);
    k_hist   <<<256,  256, 0, stream>>>(idxw, counts);
    k_gather <<<256,  256, 0, stream>>>(z, e, idxw, out, loss_sum);
    k_final  <<<1,    256, 0, stream>>>(counts, loss_sum, out);
}